// Round 6
// baseline (2163.433 us; speedup 1.0000x reference)
//
#include <hip/hip_runtime.h>
#include <math.h>

// R6: de-fused two-kernel pipeline through d_ws.
//   conv_kernel: x(1024,80,500) --64-tap FIR over C, pad 32--> y(1024,81,500) f32 in d_ws.
//     One block per n, 384 thr = 6 waves, wave owns 14 channels (84>=81).
//     Zero-padded xs rows (147x64) -> inner loop is pure ds_read+FMA (R1-proven,
//     VGPR~80, full unroll). No scan state, no ybuf -> LDS 37.9KB, lb(384,6)
//     -> 4 blocks/CU. 2 barriers/chunk, stores coalesced 256B rows.
//   scan_kernel: one block per n, 128 thr; thread c walks y[n,c,0..499] in
//     float4 groups with depth-2 prefetch (y is L2/L3-resident), PLIF scan in
//     registers, feat->LDS, 3 threads do FC.
// Fallback: if ws_size < y bytes, launch the proven R5 fused kernel.

#define CONV_THREADS 384
#define CPW      14
#define TC       64
#define NCHUNK   8         // 7*64 + 52 = 500
#define T_LEN    500
#define C_OUT    81
#define ROW0     32        // xs row = channel + 32
#define XROWS    147       // rows -32..114; zeros outside 0..79

__global__ __launch_bounds__(CONV_THREADS, 6)
void conv_kernel(const float* __restrict__ x,
                 const float* __restrict__ conv_w,
                 float* __restrict__ y)
{
    __shared__ float xs[XROWS * TC];   // 37632 B
    __shared__ float wsh[64];

    const int tid  = threadIdx.x;
    const int n    = blockIdx.x;
    const int lane = tid & 63;
    const int co0  = (tid >> 6) * CPW;

    const float* xn = x + (size_t)n * (80 * T_LEN);
    float*       yn = y + (size_t)n * (C_OUT * T_LEN);

    if (tid < 64) wsh[tid] = conv_w[tid];
    // zero pad rows (once; staging never touches them)
    for (int i = tid; i < ROW0 * TC; i += CONV_THREADS) xs[i] = 0.0f;
    for (int i = tid; i < (XROWS - 112) * TC; i += CONV_THREADS) xs[112 * TC + i] = 0.0f;
    // stage chunk 0 (80 rows x 16 float4)
    for (int i = tid; i < 80 * 16; i += CONV_THREADS) {
        const int c = i >> 4, t4 = i & 15;
        float4 v4 = *reinterpret_cast<const float4*>(xn + c * T_LEN + t4 * 4);
        *reinterpret_cast<float4*>(&xs[(c + ROW0) * TC + t4 * 4]) = v4;
    }
    __syncthreads();

    for (int chunk = 0; chunk < NCHUNK; ++chunk) {
        const int t0 = chunk * TC;

        // ---- register FIR: y[co0+r][t0+lane] = sum_k w[k]*x[co0+r+k-32] ----
        float acc[CPW];
        float win[CPW];                   // win[(k+r)%CPW] = xs row co0+k+r
        #pragma unroll
        for (int r = 0; r < CPW; ++r) acc[r] = 0.0f;
        const int base = co0 * TC + lane;
        #pragma unroll
        for (int m = 0; m < CPW - 1; ++m) win[m] = xs[base + m * TC];
        #pragma unroll
        for (int k = 0; k < 64; ++k) {
            win[(k + CPW - 1) % CPW] = xs[base + (k + CPW - 1) * TC];
            const float wk = wsh[k];
            #pragma unroll
            for (int r = 0; r < CPW; ++r)
                acc[r] = fmaf(wk, win[(k + r) % CPW], acc[r]);
        }

        const int tcols = (chunk == NCHUNK - 1) ? 52 : 64;
        if (lane < tcols) {
            #pragma unroll
            for (int r = 0; r < CPW; ++r) {
                const int co = co0 + r;
                if (co < C_OUT) yn[co * T_LEN + t0 + lane] = acc[r];
            }
        }
        __syncthreads();   // all xs reads done

        if (chunk < NCHUNK - 1) {
            const int t0n = t0 + TC;
            const int nc4 = (chunk == NCHUNK - 2) ? 13 : 16;  // last chunk: 52 cols
            for (int i = tid; i < 80 * nc4; i += CONV_THREADS) {
                int c, t4;
                if (nc4 == 16) { c = i >> 4; t4 = i & 15; }
                else           { c = i / 13; t4 = i - c * 13; }
                float4 v4 = *reinterpret_cast<const float4*>(xn + c * T_LEN + t0n + t4 * 4);
                *reinterpret_cast<float4*>(&xs[(c + ROW0) * TC + t4 * 4]) = v4;
            }
            __syncthreads();
        }
    }
}

__global__ __launch_bounds__(128)
void scan_kernel(const float* __restrict__ y,
                 const float* __restrict__ conv_b,
                 const float* __restrict__ bn_gamma,
                 const float* __restrict__ bn_beta,
                 const float* __restrict__ bn_mean,
                 const float* __restrict__ bn_var,
                 const float* __restrict__ plif_w,
                 const float* __restrict__ fc_w,
                 const float* __restrict__ fc_b,
                 float* __restrict__ out)
{
    __shared__ float feat[C_OUT];
    const int tid = threadIdx.x;
    const int n   = blockIdx.x;

    if (tid < C_OUT) {
        const float decay = 1.0f / (1.0f + expf(-plif_w[0]));
        const float inv_c = bn_gamma[tid] * rsqrtf(bn_var[tid] + 1e-5f);
        const float bb_c  = conv_b[0] * inv_c + bn_beta[tid] - bn_mean[tid] * inv_c;
        const float4* row = reinterpret_cast<const float4*>(
            y + (size_t)n * (C_OUT * T_LEN) + tid * T_LEN);   // 16B-aligned

        float v = 0.0f, cnt = 0.0f;
        float4 b0 = row[0];
        float4 b1 = row[1];
        for (int g = 0; g < 125; ++g) {            // 500 = 125 * 4
            float4 nxt = (g < 123) ? row[g + 2] : make_float4(0.f, 0.f, 0.f, 0.f);
            #pragma unroll
            for (int j = 0; j < 4; ++j) {
                const float yv = (j == 0) ? b0.x : (j == 1) ? b0.y
                               : (j == 2) ? b0.z : b0.w;
                const float xt = fmaf(yv, inv_c, bb_c);
                v = fmaf(xt - v, decay, v);
                const bool s = (v >= 1.0f);
                cnt += s ? 1.0f : 0.0f;
                v = s ? 0.0f : v;
            }
            b0 = b1; b1 = nxt;
        }
        feat[tid] = cnt * (1.0f / 500.0f);
    }
    __syncthreads();

    if (tid < 3) {
        float o = fc_b[tid];
        #pragma unroll 3
        for (int c = 0; c < C_OUT; ++c)
            o = fmaf(feat[c], fc_w[tid * C_OUT + c], o);
        out[n * 3 + tid] = o;
    }
}

// ---------------- fallback: proven R5 fused kernel ----------------
#define NTHREADS 384
#define YSTRIDE  65

__global__ __launch_bounds__(NTHREADS)
void snn_fused_kernel(const float* __restrict__ x,
                      const float* __restrict__ conv_w,
                      const float* __restrict__ conv_b,
                      const float* __restrict__ bn_gamma,
                      const float* __restrict__ bn_beta,
                      const float* __restrict__ bn_mean,
                      const float* __restrict__ bn_var,
                      const float* __restrict__ plif_w,
                      const float* __restrict__ fc_w,
                      const float* __restrict__ fc_b,
                      float* __restrict__ out)
{
    __shared__ float xs[80 * TC];
    __shared__ float ybuf[81 * YSTRIDE];
    __shared__ float wsh[64];
    __shared__ float feat[81];

    const int tid  = threadIdx.x;
    const int n    = blockIdx.x;
    const int lane = tid & 63;
    const int co0  = (tid >> 6) * CPW;

    if (tid < 64) wsh[tid] = conv_w[tid];
    const float decay = 1.0f / (1.0f + expf(-plif_w[0]));
    float v = 0.0f, cnt = 0.0f;
    float inv_c = 0.0f, bb_c = 0.0f;
    if (tid < 81) {
        inv_c = bn_gamma[tid] * rsqrtf(bn_var[tid] + 1e-5f);
        bb_c  = conv_b[0] * inv_c + bn_beta[tid] - bn_mean[tid] * inv_c;
    }
    const float* xn = x + (size_t)n * (80 * 500);

    for (int i = tid; i < 1280; i += NTHREADS) {
        const int c = i >> 4, t4 = i & 15;
        float4 v4 = *reinterpret_cast<const float4*>(xn + c * 500 + t4 * 4);
        *reinterpret_cast<float4*>(&xs[c * TC + t4 * 4]) = v4;
    }
    __syncthreads();

    for (int chunk = 0; chunk < NCHUNK; ++chunk) {
        float acc[CPW], win[CPW];
        #pragma unroll
        for (int r = 0; r < CPW; ++r) acc[r] = 0.0f;
        const int row0 = co0 - 32;
        #pragma unroll
        for (int m = 0; m < CPW - 1; ++m) {
            const int row = row0 + m;
            win[m] = ((unsigned)row < 80u) ? xs[row * TC + lane] : 0.0f;
        }
        #pragma unroll
        for (int k = 0; k < 64; ++k) {
            const int row = row0 + k + (CPW - 1);
            win[(k + CPW - 1) % CPW] = ((unsigned)row < 80u) ? xs[row * TC + lane] : 0.0f;
            const float wk = wsh[k];
            #pragma unroll
            for (int r = 0; r < CPW; ++r)
                acc[r] = fmaf(wk, win[(k + r) % CPW], acc[r]);
        }
        #pragma unroll
        for (int r = 0; r < CPW; ++r) {
            const int co = co0 + r;
            if (co < 81) ybuf[co * YSTRIDE + lane] = acc[r];
        }
        __syncthreads();

        if (tid < 81) {
            const int tcols = (chunk == NCHUNK - 1) ? 52 : 64;
            const float* yrow = &ybuf[tid * YSTRIDE];
            #pragma unroll 4
            for (int t = 0; t < tcols; ++t) {
                const float xt = fmaf(yrow[t], inv_c, bb_c);
                v = fmaf(xt - v, decay, v);
                const bool s = (v >= 1.0f);
                cnt += s ? 1.0f : 0.0f;
                v = s ? 0.0f : v;
            }
        } else if (tid >= 128 && chunk < NCHUNK - 1) {
            const int t0n = (chunk + 1) * TC;
            const int b   = tid - 128;
            #pragma unroll
            for (int it = 0; it < 5; ++it) {
                const int i = it * 256 + b;
                const int c = i >> 4, t4 = i & 15;
                int toff = t0n + t4 * 4;
                if (toff > 496) toff = 496;
                float4 v4 = *reinterpret_cast<const float4*>(xn + c * 500 + toff);
                *reinterpret_cast<float4*>(&xs[c * TC + t4 * 4]) = v4;
            }
        }
        __syncthreads();
    }

    if (tid < 81) feat[tid] = cnt * (1.0f / 500.0f);
    __syncthreads();
    if (tid < 3) {
        float o = fc_b[tid];
        #pragma unroll 3
        for (int c = 0; c < 81; ++c)
            o = fmaf(feat[c], fc_w[tid * 81 + c], o);
        out[n * 3 + tid] = o;
    }
}

extern "C" void kernel_launch(void* const* d_in, const int* in_sizes, int n_in,
                              void* d_out, int out_size, void* d_ws, size_t ws_size,
                              hipStream_t stream)
{
    const float* x        = (const float*)d_in[0];
    const float* conv_w   = (const float*)d_in[1];
    const float* conv_b   = (const float*)d_in[2];
    const float* bn_gamma = (const float*)d_in[3];
    const float* bn_beta  = (const float*)d_in[4];
    const float* bn_mean  = (const float*)d_in[5];
    const float* bn_var   = (const float*)d_in[6];
    const float* plif_w   = (const float*)d_in[7];
    const float* fc_w     = (const float*)d_in[8];
    const float* fc_b     = (const float*)d_in[9];
    float* out            = (float*)d_out;

    const size_t need = (size_t)1024 * C_OUT * T_LEN * sizeof(float);  // 165.9 MB
    if (ws_size >= need) {
        float* y = (float*)d_ws;
        conv_kernel<<<1024, CONV_THREADS, 0, stream>>>(x, conv_w, y);
        scan_kernel<<<1024, 128, 0, stream>>>(y, conv_b, bn_gamma, bn_beta,
                                              bn_mean, bn_var, plif_w,
                                              fc_w, fc_b, out);
    } else {
        snn_fused_kernel<<<1024, NTHREADS, 0, stream>>>(
            x, conv_w, conv_b, bn_gamma, bn_beta, bn_mean, bn_var,
            plif_w, fc_w, fc_b, out);
    }
}

// Round 7
// 263.913 us; speedup vs baseline: 8.1975x; 8.1975x over previous
//
#include <hip/hip_runtime.h>
#include <math.h>

// R7: de-fused, conv flattened to one block per (n,chunk).
//  conv_kernel: grid 8192 = 1024 n x 8 chunks, 384 thr = 6 waves.
//    stage x[n,:,chunk*64 +0..63] -> xs(80x64, 20.5KB) | bar | R5-proven FIR
//    (CPW=14 full unroll, predicated boundary reads, plain launch_bounds --
//    R6's (384,6) made the compiler ROLL the loop -> scratch 3.9GB) | store y.
//    One barrier, no chunk loop, zero redundant x fetch (tiles partition x).
//  scan_kernel: block per n, 256 thr; per 64-col chunk: stage y tile
//    (coalesced float4 reads, scalar LDS writes, stride 65 = proven
//    conflict-free column reads) | bar | lanes 0..80 scan | bar. FC tail.
// Fallback: proven R5 fused kernel if ws_size too small.

#define CONV_THREADS 384
#define CPW      14
#define TC       64
#define NCHUNK   8         // 7*64 + 52 = 500
#define T_LEN    500
#define C_OUT    81
#define YSTRIDE  65

__global__ __launch_bounds__(CONV_THREADS)
void conv_kernel(const float* __restrict__ x,
                 const float* __restrict__ conv_w,
                 float* __restrict__ y)
{
    __shared__ float xs[80 * TC];      // 20480 B
    __shared__ float wsh[64];

    const int tid   = threadIdx.x;
    const int bid   = blockIdx.x;
    const int n     = bid >> 3;
    const int chunk = bid & 7;
    const int lane  = tid & 63;
    const int co0   = (tid >> 6) * CPW;
    const int t0    = chunk * TC;

    const float* xn = x + (size_t)n * (80 * T_LEN);

    if (tid < 64) wsh[tid] = conv_w[tid];

    // stage 80 rows x 16 float4 (tail chunk: clamp, cols 52..63 get dup data)
    for (int i = tid; i < 1280; i += CONV_THREADS) {
        const int c  = i >> 4;
        const int t4 = i & 15;
        int toff = t0 + t4 * 4;
        if (toff > 496) toff = 496;
        float4 v4 = *reinterpret_cast<const float4*>(xn + c * T_LEN + toff);
        *reinterpret_cast<float4*>(&xs[c * TC + t4 * 4]) = v4;
    }
    __syncthreads();

    // R5-proven register FIR: y[co0+r][t0+lane] = sum_k w[k]*x[co0+r+k-32]
    float acc[CPW];
    float win[CPW];                    // win[(k+r)%CPW] = row co0+k+r-32
    #pragma unroll
    for (int r = 0; r < CPW; ++r) acc[r] = 0.0f;
    const int row0 = co0 - 32;
    #pragma unroll
    for (int m = 0; m < CPW - 1; ++m) {
        const int row = row0 + m;
        win[m] = ((unsigned)row < 80u) ? xs[row * TC + lane] : 0.0f;
    }
    #pragma unroll
    for (int k = 0; k < 64; ++k) {
        const int row = row0 + k + (CPW - 1);
        win[(k + CPW - 1) % CPW] =
            ((unsigned)row < 80u) ? xs[row * TC + lane] : 0.0f;
        const float wk = wsh[k];       // LDS broadcast
        #pragma unroll
        for (int r = 0; r < CPW; ++r)
            acc[r] = fmaf(wk, win[(k + r) % CPW], acc[r]);
    }

    const int tcols = (chunk == NCHUNK - 1) ? 52 : 64;
    if (lane < tcols) {
        float* yn = y + (size_t)n * (C_OUT * T_LEN) + t0 + lane;
        #pragma unroll
        for (int r = 0; r < CPW; ++r) {
            const int co = co0 + r;
            if (co < C_OUT) yn[co * T_LEN] = acc[r];
        }
    }
}

__global__ __launch_bounds__(256)
void scan_kernel(const float* __restrict__ y,
                 const float* __restrict__ conv_b,
                 const float* __restrict__ bn_gamma,
                 const float* __restrict__ bn_beta,
                 const float* __restrict__ bn_mean,
                 const float* __restrict__ bn_var,
                 const float* __restrict__ plif_w,
                 const float* __restrict__ fc_w,
                 const float* __restrict__ fc_b,
                 float* __restrict__ out)
{
    __shared__ float ybuf[C_OUT * YSTRIDE];   // 21060 B
    __shared__ float feat[C_OUT];

    const int tid = threadIdx.x;
    const int n   = blockIdx.x;
    const float* yn = y + (size_t)n * (C_OUT * T_LEN);

    const float decay = 1.0f / (1.0f + expf(-plif_w[0]));
    float v = 0.0f, cnt = 0.0f;
    float inv_c = 0.0f, bb_c = 0.0f;
    if (tid < C_OUT) {
        inv_c = bn_gamma[tid] * rsqrtf(bn_var[tid] + 1e-5f);
        bb_c  = conv_b[0] * inv_c + bn_beta[tid] - bn_mean[tid] * inv_c;
    }

    for (int chunk = 0; chunk < NCHUNK; ++chunk) {
        const int t0 = chunk * TC;

        // stage y[n,:,t0..t0+63] -> ybuf (coalesced f4 reads; scalar LDS
        // writes because stride 65 breaks 16B alignment on odd rows)
        for (int i = tid; i < C_OUT * 16; i += 256) {
            const int c  = i >> 4;
            const int t4 = i & 15;
            int toff = t0 + t4 * 4;
            if (toff > 496) toff = 496;         // tail dup, cols 52..63 unused
            float4 v4 = *reinterpret_cast<const float4*>(yn + c * T_LEN + toff);
            float* dst = &ybuf[c * YSTRIDE + t4 * 4];
            dst[0] = v4.x; dst[1] = v4.y; dst[2] = v4.z; dst[3] = v4.w;
        }
        __syncthreads();

        const int tcols = (chunk == NCHUNK - 1) ? 52 : 64;
        if (tid < C_OUT) {
            const float* yrow = &ybuf[tid * YSTRIDE];
            #pragma unroll 4
            for (int t = 0; t < tcols; ++t) {
                const float xt = fmaf(yrow[t], inv_c, bb_c);   // BN
                v = fmaf(xt - v, decay, v);                    // v += (x-v)*decay
                const bool s = (v >= 1.0f);
                cnt += s ? 1.0f : 0.0f;
                v = s ? 0.0f : v;
            }
        }
        __syncthreads();
    }

    if (tid < C_OUT) feat[tid] = cnt * (1.0f / 500.0f);
    __syncthreads();

    if (tid < 3) {
        float o = fc_b[tid];
        #pragma unroll 3
        for (int c = 0; c < C_OUT; ++c)
            o = fmaf(feat[c], fc_w[tid * C_OUT + c], o);
        out[n * 3 + tid] = o;
    }
}

// ---------------- fallback: proven R5 fused kernel ----------------
#define NTHREADS 384

__global__ __launch_bounds__(NTHREADS)
void snn_fused_kernel(const float* __restrict__ x,
                      const float* __restrict__ conv_w,
                      const float* __restrict__ conv_b,
                      const float* __restrict__ bn_gamma,
                      const float* __restrict__ bn_beta,
                      const float* __restrict__ bn_mean,
                      const float* __restrict__ bn_var,
                      const float* __restrict__ plif_w,
                      const float* __restrict__ fc_w,
                      const float* __restrict__ fc_b,
                      float* __restrict__ out)
{
    __shared__ float xs[80 * TC];
    __shared__ float ybuf[81 * YSTRIDE];
    __shared__ float wsh[64];
    __shared__ float feat[81];

    const int tid  = threadIdx.x;
    const int n    = blockIdx.x;
    const int lane = tid & 63;
    const int co0  = (tid >> 6) * CPW;

    if (tid < 64) wsh[tid] = conv_w[tid];
    const float decay = 1.0f / (1.0f + expf(-plif_w[0]));
    float v = 0.0f, cnt = 0.0f;
    float inv_c = 0.0f, bb_c = 0.0f;
    if (tid < 81) {
        inv_c = bn_gamma[tid] * rsqrtf(bn_var[tid] + 1e-5f);
        bb_c  = conv_b[0] * inv_c + bn_beta[tid] - bn_mean[tid] * inv_c;
    }
    const float* xn = x + (size_t)n * (80 * 500);

    for (int i = tid; i < 1280; i += NTHREADS) {
        const int c = i >> 4, t4 = i & 15;
        float4 v4 = *reinterpret_cast<const float4*>(xn + c * 500 + t4 * 4);
        *reinterpret_cast<float4*>(&xs[c * TC + t4 * 4]) = v4;
    }
    __syncthreads();

    for (int chunk = 0; chunk < NCHUNK; ++chunk) {
        float acc[CPW], win[CPW];
        #pragma unroll
        for (int r = 0; r < CPW; ++r) acc[r] = 0.0f;
        const int row0 = co0 - 32;
        #pragma unroll
        for (int m = 0; m < CPW - 1; ++m) {
            const int row = row0 + m;
            win[m] = ((unsigned)row < 80u) ? xs[row * TC + lane] : 0.0f;
        }
        #pragma unroll
        for (int k = 0; k < 64; ++k) {
            const int row = row0 + k + (CPW - 1);
            win[(k + CPW - 1) % CPW] = ((unsigned)row < 80u) ? xs[row * TC + lane] : 0.0f;
            const float wk = wsh[k];
            #pragma unroll
            for (int r = 0; r < CPW; ++r)
                acc[r] = fmaf(wk, win[(k + r) % CPW], acc[r]);
        }
        #pragma unroll
        for (int r = 0; r < CPW; ++r) {
            const int co = co0 + r;
            if (co < 81) ybuf[co * YSTRIDE + lane] = acc[r];
        }
        __syncthreads();

        if (tid < 81) {
            const int tcols = (chunk == NCHUNK - 1) ? 52 : 64;
            const float* yrow = &ybuf[tid * YSTRIDE];
            #pragma unroll 4
            for (int t = 0; t < tcols; ++t) {
                const float xt = fmaf(yrow[t], inv_c, bb_c);
                v = fmaf(xt - v, decay, v);
                const bool s = (v >= 1.0f);
                cnt += s ? 1.0f : 0.0f;
                v = s ? 0.0f : v;
            }
        } else if (tid >= 128 && chunk < NCHUNK - 1) {
            const int t0n = (chunk + 1) * TC;
            const int b   = tid - 128;
            #pragma unroll
            for (int it = 0; it < 5; ++it) {
                const int i = it * 256 + b;
                const int c = i >> 4, t4 = i & 15;
                int toff = t0n + t4 * 4;
                if (toff > 496) toff = 496;
                float4 v4 = *reinterpret_cast<const float4*>(xn + c * 500 + toff);
                *reinterpret_cast<float4*>(&xs[c * TC + t4 * 4]) = v4;
            }
        }
        __syncthreads();
    }

    if (tid < 81) feat[tid] = cnt * (1.0f / 500.0f);
    __syncthreads();
    if (tid < 3) {
        float o = fc_b[tid];
        #pragma unroll 3
        for (int c = 0; c < 81; ++c)
            o = fmaf(feat[c], fc_w[tid * 81 + c], o);
        out[n * 3 + tid] = o;
    }
}

extern "C" void kernel_launch(void* const* d_in, const int* in_sizes, int n_in,
                              void* d_out, int out_size, void* d_ws, size_t ws_size,
                              hipStream_t stream)
{
    const float* x        = (const float*)d_in[0];
    const float* conv_w   = (const float*)d_in[1];
    const float* conv_b   = (const float*)d_in[2];
    const float* bn_gamma = (const float*)d_in[3];
    const float* bn_beta  = (const float*)d_in[4];
    const float* bn_mean  = (const float*)d_in[5];
    const float* bn_var   = (const float*)d_in[6];
    const float* plif_w   = (const float*)d_in[7];
    const float* fc_w     = (const float*)d_in[8];
    const float* fc_b     = (const float*)d_in[9];
    float* out            = (float*)d_out;

    const size_t need = (size_t)1024 * C_OUT * T_LEN * sizeof(float);  // 165.9 MB
    if (ws_size >= need) {
        float* y = (float*)d_ws;
        conv_kernel<<<1024 * NCHUNK, CONV_THREADS, 0, stream>>>(x, conv_w, y);
        scan_kernel<<<1024, 256, 0, stream>>>(y, conv_b, bn_gamma, bn_beta,
                                              bn_mean, bn_var, plif_w,
                                              fc_w, fc_b, out);
    } else {
        snn_fused_kernel<<<1024, NTHREADS, 0, stream>>>(
            x, conv_w, conv_b, bn_gamma, bn_beta, bn_mean, bn_var,
            plif_w, fc_w, fc_b, out);
    }
}

// Round 8
// 235.031 us; speedup vs baseline: 9.2049x; 1.1229x over previous
//
#include <hip/hip_runtime.h>
#include <math.h>

// R8: de-fused. conv = one block per (n,chunk), 512 thr = 8 waves, CPW=11
// (8*11=88 >= 81). CPW drop 14->11 targets VGPR <= 64: the m69 halving law
// puts 65..128 VGPR in the 16-wave/CU bucket (R7: VGPR=80 -> 2 blocks/CU,
// occupancy 18%, VALUBusy 40%); <=64 VGPR -> 32 waves/CU -> 4 blocks/CU.
// Plain launch_bounds (R6 lesson: min-waves coercion rolls the FIR loop ->
// scratch). 704-FMA body < proven-unrollable 896.
// scan_kernel + fused fallback unchanged from R7 (proven).

#define CONV_THREADS 512
#define CPW      11
#define FCPW     14        // fallback kernel's proven CPW
#define TC       64
#define NCHUNK   8         // 7*64 + 52 = 500
#define T_LEN    500
#define C_OUT    81
#define YSTRIDE  65

__global__ __launch_bounds__(CONV_THREADS)
void conv_kernel(const float* __restrict__ x,
                 const float* __restrict__ conv_w,
                 float* __restrict__ y)
{
    __shared__ float xs[80 * TC];      // 20480 B
    __shared__ float wsh[64];

    const int tid   = threadIdx.x;
    const int bid   = blockIdx.x;
    const int n     = bid >> 3;
    const int chunk = bid & 7;
    const int lane  = tid & 63;
    const int co0   = (tid >> 6) * CPW;
    const int t0    = chunk * TC;

    const float* xn = x + (size_t)n * (80 * T_LEN);

    if (tid < 64) wsh[tid] = conv_w[tid];

    // stage 80 rows x 16 float4 (tail chunk: clamp; cols 52..63 dup, unused)
    for (int i = tid; i < 1280; i += CONV_THREADS) {
        const int c  = i >> 4;
        const int t4 = i & 15;
        int toff = t0 + t4 * 4;
        if (toff > 496) toff = 496;
        float4 v4 = *reinterpret_cast<const float4*>(xn + c * T_LEN + toff);
        *reinterpret_cast<float4*>(&xs[c * TC + t4 * 4]) = v4;
    }
    __syncthreads();

    // register FIR: y[co0+r][t0+lane] = sum_k w[k]*x[co0+r+k-32]
    float acc[CPW];
    float win[CPW];                    // win[(k+r)%CPW] = row co0+k+r-32
    #pragma unroll
    for (int r = 0; r < CPW; ++r) acc[r] = 0.0f;
    const int row0 = co0 - 32;
    #pragma unroll
    for (int m = 0; m < CPW - 1; ++m) {
        const int row = row0 + m;
        win[m] = ((unsigned)row < 80u) ? xs[row * TC + lane] : 0.0f;
    }
    #pragma unroll
    for (int k = 0; k < 64; ++k) {
        const int row = row0 + k + (CPW - 1);
        win[(k + CPW - 1) % CPW] =
            ((unsigned)row < 80u) ? xs[row * TC + lane] : 0.0f;
        const float wk = wsh[k];       // LDS broadcast
        #pragma unroll
        for (int r = 0; r < CPW; ++r)
            acc[r] = fmaf(wk, win[(k + r) % CPW], acc[r]);
    }

    const int tcols = (chunk == NCHUNK - 1) ? 52 : 64;
    if (lane < tcols) {
        float* yn = y + (size_t)n * (C_OUT * T_LEN) + t0 + lane;
        #pragma unroll
        for (int r = 0; r < CPW; ++r) {
            const int co = co0 + r;
            if (co < C_OUT) yn[co * T_LEN] = acc[r];
        }
    }
}

__global__ __launch_bounds__(256)
void scan_kernel(const float* __restrict__ y,
                 const float* __restrict__ conv_b,
                 const float* __restrict__ bn_gamma,
                 const float* __restrict__ bn_beta,
                 const float* __restrict__ bn_mean,
                 const float* __restrict__ bn_var,
                 const float* __restrict__ plif_w,
                 const float* __restrict__ fc_w,
                 const float* __restrict__ fc_b,
                 float* __restrict__ out)
{
    __shared__ float ybuf[C_OUT * YSTRIDE];   // 21060 B
    __shared__ float feat[C_OUT];

    const int tid = threadIdx.x;
    const int n   = blockIdx.x;
    const float* yn = y + (size_t)n * (C_OUT * T_LEN);

    const float decay = 1.0f / (1.0f + expf(-plif_w[0]));
    float v = 0.0f, cnt = 0.0f;
    float inv_c = 0.0f, bb_c = 0.0f;
    if (tid < C_OUT) {
        inv_c = bn_gamma[tid] * rsqrtf(bn_var[tid] + 1e-5f);
        bb_c  = conv_b[0] * inv_c + bn_beta[tid] - bn_mean[tid] * inv_c;
    }

    for (int chunk = 0; chunk < NCHUNK; ++chunk) {
        const int t0 = chunk * TC;

        for (int i = tid; i < C_OUT * 16; i += 256) {
            const int c  = i >> 4;
            const int t4 = i & 15;
            int toff = t0 + t4 * 4;
            if (toff > 496) toff = 496;         // tail dup, cols 52..63 unused
            float4 v4 = *reinterpret_cast<const float4*>(yn + c * T_LEN + toff);
            float* dst = &ybuf[c * YSTRIDE + t4 * 4];
            dst[0] = v4.x; dst[1] = v4.y; dst[2] = v4.z; dst[3] = v4.w;
        }
        __syncthreads();

        const int tcols = (chunk == NCHUNK - 1) ? 52 : 64;
        if (tid < C_OUT) {
            const float* yrow = &ybuf[tid * YSTRIDE];
            #pragma unroll 4
            for (int t = 0; t < tcols; ++t) {
                const float xt = fmaf(yrow[t], inv_c, bb_c);   // BN
                v = fmaf(xt - v, decay, v);                    // v += (x-v)*decay
                const bool s = (v >= 1.0f);
                cnt += s ? 1.0f : 0.0f;
                v = s ? 0.0f : v;
            }
        }
        __syncthreads();
    }

    if (tid < C_OUT) feat[tid] = cnt * (1.0f / 500.0f);
    __syncthreads();

    if (tid < 3) {
        float o = fc_b[tid];
        #pragma unroll 3
        for (int c = 0; c < C_OUT; ++c)
            o = fmaf(feat[c], fc_w[tid * C_OUT + c], o);
        out[n * 3 + tid] = o;
    }
}

// ---------------- fallback: proven R5 fused kernel ----------------
#define NTHREADS 384

__global__ __launch_bounds__(NTHREADS)
void snn_fused_kernel(const float* __restrict__ x,
                      const float* __restrict__ conv_w,
                      const float* __restrict__ conv_b,
                      const float* __restrict__ bn_gamma,
                      const float* __restrict__ bn_beta,
                      const float* __restrict__ bn_mean,
                      const float* __restrict__ bn_var,
                      const float* __restrict__ plif_w,
                      const float* __restrict__ fc_w,
                      const float* __restrict__ fc_b,
                      float* __restrict__ out)
{
    __shared__ float xs[80 * TC];
    __shared__ float ybuf[81 * YSTRIDE];
    __shared__ float wsh[64];
    __shared__ float feat[81];

    const int tid  = threadIdx.x;
    const int n    = blockIdx.x;
    const int lane = tid & 63;
    const int co0  = (tid >> 6) * FCPW;

    if (tid < 64) wsh[tid] = conv_w[tid];
    const float decay = 1.0f / (1.0f + expf(-plif_w[0]));
    float v = 0.0f, cnt = 0.0f;
    float inv_c = 0.0f, bb_c = 0.0f;
    if (tid < 81) {
        inv_c = bn_gamma[tid] * rsqrtf(bn_var[tid] + 1e-5f);
        bb_c  = conv_b[0] * inv_c + bn_beta[tid] - bn_mean[tid] * inv_c;
    }
    const float* xn = x + (size_t)n * (80 * 500);

    for (int i = tid; i < 1280; i += NTHREADS) {
        const int c = i >> 4, t4 = i & 15;
        float4 v4 = *reinterpret_cast<const float4*>(xn + c * 500 + t4 * 4);
        *reinterpret_cast<float4*>(&xs[c * TC + t4 * 4]) = v4;
    }
    __syncthreads();

    for (int chunk = 0; chunk < NCHUNK; ++chunk) {
        float acc[FCPW], win[FCPW];
        #pragma unroll
        for (int r = 0; r < FCPW; ++r) acc[r] = 0.0f;
        const int row0 = co0 - 32;
        #pragma unroll
        for (int m = 0; m < FCPW - 1; ++m) {
            const int row = row0 + m;
            win[m] = ((unsigned)row < 80u) ? xs[row * TC + lane] : 0.0f;
        }
        #pragma unroll
        for (int k = 0; k < 64; ++k) {
            const int row = row0 + k + (FCPW - 1);
            win[(k + FCPW - 1) % FCPW] = ((unsigned)row < 80u) ? xs[row * TC + lane] : 0.0f;
            const float wk = wsh[k];
            #pragma unroll
            for (int r = 0; r < FCPW; ++r)
                acc[r] = fmaf(wk, win[(k + r) % FCPW], acc[r]);
        }
        #pragma unroll
        for (int r = 0; r < FCPW; ++r) {
            const int co = co0 + r;
            if (co < 81) ybuf[co * YSTRIDE + lane] = acc[r];
        }
        __syncthreads();

        if (tid < 81) {
            const int tcols = (chunk == NCHUNK - 1) ? 52 : 64;
            const float* yrow = &ybuf[tid * YSTRIDE];
            #pragma unroll 4
            for (int t = 0; t < tcols; ++t) {
                const float xt = fmaf(yrow[t], inv_c, bb_c);
                v = fmaf(xt - v, decay, v);
                const bool s = (v >= 1.0f);
                cnt += s ? 1.0f : 0.0f;
                v = s ? 0.0f : v;
            }
        } else if (tid >= 128 && chunk < NCHUNK - 1) {
            const int t0n = (chunk + 1) * TC;
            const int b   = tid - 128;
            #pragma unroll
            for (int it = 0; it < 5; ++it) {
                const int i = it * 256 + b;
                const int c = i >> 4, t4 = i & 15;
                int toff = t0n + t4 * 4;
                if (toff > 496) toff = 496;
                float4 v4 = *reinterpret_cast<const float4*>(xn + c * 500 + toff);
                *reinterpret_cast<float4*>(&xs[c * TC + t4 * 4]) = v4;
            }
        }
        __syncthreads();
    }

    if (tid < 81) feat[tid] = cnt * (1.0f / 500.0f);
    __syncthreads();
    if (tid < 3) {
        float o = fc_b[tid];
        #pragma unroll 3
        for (int c = 0; c < 81; ++c)
            o = fmaf(feat[c], fc_w[tid * 81 + c], o);
        out[n * 3 + tid] = o;
    }
}

extern "C" void kernel_launch(void* const* d_in, const int* in_sizes, int n_in,
                              void* d_out, int out_size, void* d_ws, size_t ws_size,
                              hipStream_t stream)
{
    const float* x        = (const float*)d_in[0];
    const float* conv_w   = (const float*)d_in[1];
    const float* conv_b   = (const float*)d_in[2];
    const float* bn_gamma = (const float*)d_in[3];
    const float* bn_beta  = (const float*)d_in[4];
    const float* bn_mean  = (const float*)d_in[5];
    const float* bn_var   = (const float*)d_in[6];
    const float* plif_w   = (const float*)d_in[7];
    const float* fc_w     = (const float*)d_in[8];
    const float* fc_b     = (const float*)d_in[9];
    float* out            = (float*)d_out;

    const size_t need = (size_t)1024 * C_OUT * T_LEN * sizeof(float);  // 165.9 MB
    if (ws_size >= need) {
        float* y = (float*)d_ws;
        conv_kernel<<<1024 * NCHUNK, CONV_THREADS, 0, stream>>>(x, conv_w, y);
        scan_kernel<<<1024, 256, 0, stream>>>(y, conv_b, bn_gamma, bn_beta,
                                              bn_mean, bn_var, plif_w,
                                              fc_w, fc_b, out);
    } else {
        snn_fused_kernel<<<1024, NTHREADS, 0, stream>>>(
            x, conv_w, conv_b, bn_gamma, bn_beta, bn_mean, bn_var,
            plif_w, fc_w, fc_b, out);
    }
}

// Round 9
// 213.202 us; speedup vs baseline: 10.1473x; 1.1024x over previous
//
#include <hip/hip_runtime.h>
#include <math.h>

// R9: de-fused; conv is PERSISTENT per-n with double-buffered LDS.
//  conv_kernel: 1024 blocks (one per n), 512 thr = 8 waves, CPW=11
//    (R8's proven FIR codegen, VGPR=80, zero scratch). Per 64-col chunk:
//    FIR from xs[cur] -> store y -> stage chunk+1 into xs[cur^1] -> barrier.
//    Stage latency hides under other waves' FIR; one barrier per chunk;
//    no short-block churn (R7/R8: 8192 pulse-blocks, stage unhidden).
//    LDS 2x20.5K+w = 41.2KB -> 3 blocks/CU = 24 waves = VGPR cap.
//  scan_kernel unchanged (proven, ~19us). Fallback: proven R5 fused.

#define CONV_THREADS 512
#define CPW      11
#define FCPW     14        // fallback kernel's proven CPW
#define TC       64
#define NCHUNK   8         // 7*64 + 52 = 500
#define T_LEN    500
#define C_OUT    81
#define YSTRIDE  65

__global__ __launch_bounds__(CONV_THREADS)
void conv_kernel(const float* __restrict__ x,
                 const float* __restrict__ conv_w,
                 float* __restrict__ y)
{
    __shared__ float xs[2][80 * TC];   // 2 x 20480 B
    __shared__ float wsh[64];

    const int tid  = threadIdx.x;
    const int n    = blockIdx.x;
    const int lane = tid & 63;
    const int co0  = (tid >> 6) * CPW;

    const float* xn = x + (size_t)n * (80 * T_LEN);
    float*       yn = y + (size_t)n * (C_OUT * T_LEN);

    if (tid < 64) wsh[tid] = conv_w[tid];

    // prologue: stage chunk 0 -> xs[0]
    for (int i = tid; i < 1280; i += CONV_THREADS) {
        const int c  = i >> 4;
        const int t4 = i & 15;
        float4 v4 = *reinterpret_cast<const float4*>(xn + c * T_LEN + t4 * 4);
        *reinterpret_cast<float4*>(&xs[0][c * TC + t4 * 4]) = v4;
    }
    __syncthreads();

    for (int chunk = 0; chunk < NCHUNK; ++chunk) {
        const int cur = chunk & 1;
        const int t0  = chunk * TC;
        const float* xsc = xs[cur];

        // ---- register FIR (R8-proven): y[co0+r][t0+lane] ----
        float acc[CPW];
        float win[CPW];                // win[(k+r)%CPW] = row co0+k+r-32
        #pragma unroll
        for (int r = 0; r < CPW; ++r) acc[r] = 0.0f;
        const int row0 = co0 - 32;
        #pragma unroll
        for (int m = 0; m < CPW - 1; ++m) {
            const int row = row0 + m;
            win[m] = ((unsigned)row < 80u) ? xsc[row * TC + lane] : 0.0f;
        }
        #pragma unroll
        for (int k = 0; k < 64; ++k) {
            const int row = row0 + k + (CPW - 1);
            win[(k + CPW - 1) % CPW] =
                ((unsigned)row < 80u) ? xsc[row * TC + lane] : 0.0f;
            const float wk = wsh[k];   // LDS broadcast
            #pragma unroll
            for (int r = 0; r < CPW; ++r)
                acc[r] = fmaf(wk, win[(k + r) % CPW], acc[r]);
        }

        const int tcols = (chunk == NCHUNK - 1) ? 52 : 64;
        if (lane < tcols) {
            float* yp = yn + t0 + lane;
            #pragma unroll
            for (int r = 0; r < CPW; ++r) {
                const int co = co0 + r;
                if (co < C_OUT) yp[co * T_LEN] = acc[r];
            }
        }

        // ---- stage chunk+1 -> xs[cur^1] (latency under other waves' FIR) ----
        if (chunk < NCHUNK - 1) {
            const int t0n = t0 + TC;
            for (int i = tid; i < 1280; i += CONV_THREADS) {
                const int c  = i >> 4;
                const int t4 = i & 15;
                int toff = t0n + t4 * 4;
                if (toff > 496) toff = 496;   // tail dup; cols 52..63 unused
                float4 v4 = *reinterpret_cast<const float4*>(xn + c * T_LEN + toff);
                *reinterpret_cast<float4*>(&xs[cur ^ 1][c * TC + t4 * 4]) = v4;
            }
        }
        __syncthreads();   // FIR reads + stage writes of this iter complete
    }
}

__global__ __launch_bounds__(256)
void scan_kernel(const float* __restrict__ y,
                 const float* __restrict__ conv_b,
                 const float* __restrict__ bn_gamma,
                 const float* __restrict__ bn_beta,
                 const float* __restrict__ bn_mean,
                 const float* __restrict__ bn_var,
                 const float* __restrict__ plif_w,
                 const float* __restrict__ fc_w,
                 const float* __restrict__ fc_b,
                 float* __restrict__ out)
{
    __shared__ float ybuf[C_OUT * YSTRIDE];   // 21060 B
    __shared__ float feat[C_OUT];

    const int tid = threadIdx.x;
    const int n   = blockIdx.x;
    const float* yn = y + (size_t)n * (C_OUT * T_LEN);

    const float decay = 1.0f / (1.0f + expf(-plif_w[0]));
    float v = 0.0f, cnt = 0.0f;
    float inv_c = 0.0f, bb_c = 0.0f;
    if (tid < C_OUT) {
        inv_c = bn_gamma[tid] * rsqrtf(bn_var[tid] + 1e-5f);
        bb_c  = conv_b[0] * inv_c + bn_beta[tid] - bn_mean[tid] * inv_c;
    }

    for (int chunk = 0; chunk < NCHUNK; ++chunk) {
        const int t0 = chunk * TC;

        for (int i = tid; i < C_OUT * 16; i += 256) {
            const int c  = i >> 4;
            const int t4 = i & 15;
            int toff = t0 + t4 * 4;
            if (toff > 496) toff = 496;         // tail dup, cols 52..63 unused
            float4 v4 = *reinterpret_cast<const float4*>(yn + c * T_LEN + toff);
            float* dst = &ybuf[c * YSTRIDE + t4 * 4];
            dst[0] = v4.x; dst[1] = v4.y; dst[2] = v4.z; dst[3] = v4.w;
        }
        __syncthreads();

        const int tcols = (chunk == NCHUNK - 1) ? 52 : 64;
        if (tid < C_OUT) {
            const float* yrow = &ybuf[tid * YSTRIDE];
            #pragma unroll 4
            for (int t = 0; t < tcols; ++t) {
                const float xt = fmaf(yrow[t], inv_c, bb_c);   // BN
                v = fmaf(xt - v, decay, v);                    // v += (x-v)*decay
                const bool s = (v >= 1.0f);
                cnt += s ? 1.0f : 0.0f;
                v = s ? 0.0f : v;
            }
        }
        __syncthreads();
    }

    if (tid < C_OUT) feat[tid] = cnt * (1.0f / 500.0f);
    __syncthreads();

    if (tid < 3) {
        float o = fc_b[tid];
        #pragma unroll 3
        for (int c = 0; c < C_OUT; ++c)
            o = fmaf(feat[c], fc_w[tid * C_OUT + c], o);
        out[n * 3 + tid] = o;
    }
}

// ---------------- fallback: proven R5 fused kernel ----------------
#define NTHREADS 384

__global__ __launch_bounds__(NTHREADS)
void snn_fused_kernel(const float* __restrict__ x,
                      const float* __restrict__ conv_w,
                      const float* __restrict__ conv_b,
                      const float* __restrict__ bn_gamma,
                      const float* __restrict__ bn_beta,
                      const float* __restrict__ bn_mean,
                      const float* __restrict__ bn_var,
                      const float* __restrict__ plif_w,
                      const float* __restrict__ fc_w,
                      const float* __restrict__ fc_b,
                      float* __restrict__ out)
{
    __shared__ float xs[80 * TC];
    __shared__ float ybuf[81 * YSTRIDE];
    __shared__ float wsh[64];
    __shared__ float feat[81];

    const int tid  = threadIdx.x;
    const int n    = blockIdx.x;
    const int lane = tid & 63;
    const int co0  = (tid >> 6) * FCPW;

    if (tid < 64) wsh[tid] = conv_w[tid];
    const float decay = 1.0f / (1.0f + expf(-plif_w[0]));
    float v = 0.0f, cnt = 0.0f;
    float inv_c = 0.0f, bb_c = 0.0f;
    if (tid < 81) {
        inv_c = bn_gamma[tid] * rsqrtf(bn_var[tid] + 1e-5f);
        bb_c  = conv_b[0] * inv_c + bn_beta[tid] - bn_mean[tid] * inv_c;
    }
    const float* xn = x + (size_t)n * (80 * 500);

    for (int i = tid; i < 1280; i += NTHREADS) {
        const int c = i >> 4, t4 = i & 15;
        float4 v4 = *reinterpret_cast<const float4*>(xn + c * 500 + t4 * 4);
        *reinterpret_cast<float4*>(&xs[c * TC + t4 * 4]) = v4;
    }
    __syncthreads();

    for (int chunk = 0; chunk < NCHUNK; ++chunk) {
        float acc[FCPW], win[FCPW];
        #pragma unroll
        for (int r = 0; r < FCPW; ++r) acc[r] = 0.0f;
        const int row0 = co0 - 32;
        #pragma unroll
        for (int m = 0; m < FCPW - 1; ++m) {
            const int row = row0 + m;
            win[m] = ((unsigned)row < 80u) ? xs[row * TC + lane] : 0.0f;
        }
        #pragma unroll
        for (int k = 0; k < 64; ++k) {
            const int row = row0 + k + (FCPW - 1);
            win[(k + FCPW - 1) % FCPW] = ((unsigned)row < 80u) ? xs[row * TC + lane] : 0.0f;
            const float wk = wsh[k];
            #pragma unroll
            for (int r = 0; r < FCPW; ++r)
                acc[r] = fmaf(wk, win[(k + r) % FCPW], acc[r]);
        }
        #pragma unroll
        for (int r = 0; r < FCPW; ++r) {
            const int co = co0 + r;
            if (co < 81) ybuf[co * YSTRIDE + lane] = acc[r];
        }
        __syncthreads();

        if (tid < 81) {
            const int tcols = (chunk == NCHUNK - 1) ? 52 : 64;
            const float* yrow = &ybuf[tid * YSTRIDE];
            #pragma unroll 4
            for (int t = 0; t < tcols; ++t) {
                const float xt = fmaf(yrow[t], inv_c, bb_c);
                v = fmaf(xt - v, decay, v);
                const bool s = (v >= 1.0f);
                cnt += s ? 1.0f : 0.0f;
                v = s ? 0.0f : v;
            }
        } else if (tid >= 128 && chunk < NCHUNK - 1) {
            const int t0n = (chunk + 1) * TC;
            const int b   = tid - 128;
            #pragma unroll
            for (int it = 0; it < 5; ++it) {
                const int i = it * 256 + b;
                const int c = i >> 4, t4 = i & 15;
                int toff = t0n + t4 * 4;
                if (toff > 496) toff = 496;
                float4 v4 = *reinterpret_cast<const float4*>(xn + c * 500 + toff);
                *reinterpret_cast<float4*>(&xs[c * TC + t4 * 4]) = v4;
            }
        }
        __syncthreads();
    }

    if (tid < 81) feat[tid] = cnt * (1.0f / 500.0f);
    __syncthreads();
    if (tid < 3) {
        float o = fc_b[tid];
        #pragma unroll 3
        for (int c = 0; c < 81; ++c)
            o = fmaf(feat[c], fc_w[tid * 81 + c], o);
        out[n * 3 + tid] = o;
    }
}

extern "C" void kernel_launch(void* const* d_in, const int* in_sizes, int n_in,
                              void* d_out, int out_size, void* d_ws, size_t ws_size,
                              hipStream_t stream)
{
    const float* x        = (const float*)d_in[0];
    const float* conv_w   = (const float*)d_in[1];
    const float* conv_b   = (const float*)d_in[2];
    const float* bn_gamma = (const float*)d_in[3];
    const float* bn_beta  = (const float*)d_in[4];
    const float* bn_mean  = (const float*)d_in[5];
    const float* bn_var   = (const float*)d_in[6];
    const float* plif_w   = (const float*)d_in[7];
    const float* fc_w     = (const float*)d_in[8];
    const float* fc_b     = (const float*)d_in[9];
    float* out            = (float*)d_out;

    const size_t need = (size_t)1024 * C_OUT * T_LEN * sizeof(float);  // 165.9 MB
    if (ws_size >= need) {
        float* y = (float*)d_ws;
        conv_kernel<<<1024, CONV_THREADS, 0, stream>>>(x, conv_w, y);
        scan_kernel<<<1024, 256, 0, stream>>>(y, conv_b, bn_gamma, bn_beta,
                                              bn_mean, bn_var, plif_w,
                                              fc_w, fc_b, out);
    } else {
        snn_fused_kernel<<<1024, NTHREADS, 0, stream>>>(
            x, conv_w, conv_b, bn_gamma, bn_beta, bn_mean, bn_var,
            plif_w, fc_w, fc_b, out);
    }
}

// Round 10
// 132.879 us; speedup vs baseline: 16.2812x; 1.6045x over previous
//
#include <hip/hip_runtime.h>
#include <math.h>

// R10: fused single kernel, WAVE-ROLE SPECIALIZATION (producer/consumer).
// x:(1024,80,500) f32. One block per n. 640 thr = 10 waves:
//   waves 0..7  : FIR producers. wave w owns channels co0=11w..co0+10
//                 (88>=81). Padded xs (151 rows: row j = channel j-32,
//                 zeros outside 0..79) -> inner loop is PURE ds_read+fma
//                 (no boundary cndmask). Proven CPW=11 full-unroll codegen.
//   waves 8..9  : scan+stage consumers. lane ch<81 advances the PLIF scan
//                 for chunk c-1 from ybuf[(c-1)&1]; all 128 lanes also
//                 stage chunk c+1 (global->reg->LDS; regs live only across
//                 the small scan loop, never across the FIR -> no spill).
// Double-buffered xs AND ybuf => all four LDS regions disjoint per iter
// => ONE barrier per chunk; FIR/scan/stage run concurrently on different
// waves. No y workspace traffic (R9 paid 177MB write + 166MB read).
// LDS ~117 KiB (gfx950 allows >=128 KiB/workgroup, cf. m201) -> 1 block/CU,
// 2 FIR waves per SIMD, balanced.

#define NTH      640
#define NFIR     512       // threads in FIR waves
#define CPW      11
#define TC       64
#define XROWS    151       // max padded row read = co0(77)+73 = 150
#define YSTRIDE  65        // +1 pad: conflict-free column reads in scan
#define NCHUNK   8         // 7*64 + 52 = 500
#define T_LEN    500
#define C_OUT    81

__global__ __launch_bounds__(NTH)
void snn_fused_ps_kernel(const float* __restrict__ x,
                         const float* __restrict__ conv_w,
                         const float* __restrict__ conv_b,
                         const float* __restrict__ bn_gamma,
                         const float* __restrict__ bn_beta,
                         const float* __restrict__ bn_mean,
                         const float* __restrict__ bn_var,
                         const float* __restrict__ plif_w,
                         const float* __restrict__ fc_w,
                         const float* __restrict__ fc_b,
                         float* __restrict__ out)
{
    __shared__ float xs[2][XROWS * TC];        // 2 x 38656 B
    __shared__ float ybuf[2][C_OUT * YSTRIDE]; // 2 x 21060 B
    __shared__ float wsh[64];
    __shared__ float feat[C_OUT];              // total ~117.3 KiB

    const int tid  = threadIdx.x;
    const int n    = blockIdx.x;
    const float* xn = x + (size_t)n * (80 * T_LEN);

    if (tid < 64) wsh[tid] = conv_w[tid];

    // ---- zero the FIR pad rows of BOTH buffers (written once, never again)
    for (int i = tid; i < 32 * TC; i += NTH) { xs[0][i] = 0.0f; xs[1][i] = 0.0f; }
    for (int i = tid; i < (XROWS - 112) * TC; i += NTH) {
        xs[0][112 * TC + i] = 0.0f; xs[1][112 * TC + i] = 0.0f;
    }
    // ---- stage chunk 0 -> xs[0] rows 32..111 (all threads, 2 f4 each)
    for (int i = tid; i < 1280; i += NTH) {
        const int cr = i >> 4, t4 = i & 15;
        float4 v4 = *reinterpret_cast<const float4*>(xn + cr * T_LEN + t4 * 4);
        *reinterpret_cast<float4*>(&xs[0][(cr + 32) * TC + t4 * 4]) = v4;
    }

    // scan-wave per-lane state (threads 512..639; channel = tid-512)
    float v = 0.0f, cnt = 0.0f, inv_c = 0.0f, bb_c = 0.0f, decay = 0.0f;
    if (tid >= NFIR) {
        const int ch = tid - NFIR;
        decay = 1.0f / (1.0f + expf(-plif_w[0]));
        if (ch < C_OUT) {
            inv_c = bn_gamma[ch] * rsqrtf(bn_var[ch] + 1e-5f);
            bb_c  = conv_b[0] * inv_c + bn_beta[ch] - bn_mean[ch] * inv_c;
        }
    }
    __syncthreads();

    for (int c = 0; c < NCHUNK; ++c) {
        const int b = c & 1;

        if (tid < NFIR) {
            // ================= FIR producers =================
            const int lane = tid & 63;
            const int co0  = (tid >> 6) * CPW;
            const float* xsb = xs[b];

            float acc[CPW];
            float win[CPW];                   // win[(k+r)%CPW] = padded row co0+k+r
            #pragma unroll
            for (int r = 0; r < CPW; ++r) acc[r] = 0.0f;
            const int base = co0 * TC + lane;
            #pragma unroll
            for (int m = 0; m < CPW - 1; ++m) win[m] = xsb[base + m * TC];
            #pragma unroll
            for (int k = 0; k < 64; ++k) {
                win[(k + CPW - 1) % CPW] = xsb[base + (k + CPW - 1) * TC];
                const float wk = wsh[k];      // LDS broadcast
                #pragma unroll
                for (int r = 0; r < CPW; ++r)
                    acc[r] = fmaf(wk, win[(k + r) % CPW], acc[r]);
            }
            #pragma unroll
            for (int r = 0; r < CPW; ++r) {
                const int co = co0 + r;
                if (co < C_OUT) ybuf[b][co * YSTRIDE + lane] = acc[r];
            }
        } else {
            // ============ scan + stage consumers ============
            const int sid = tid - NFIR;       // 0..127

            // 1) issue next chunk's global loads (latency hides under scan)
            float4 pf[10];
            if (c < NCHUNK - 1) {
                const int t0n = (c + 1) * TC;
                #pragma unroll
                for (int s = 0; s < 10; ++s) {
                    const int i  = s * 128 + sid;   // 1280 items
                    const int cr = i >> 4, t4 = i & 15;
                    int toff = t0n + t4 * 4;
                    if (toff > 496) toff = 496;     // tail dup; cols 52..63 unused
                    pf[s] = *reinterpret_cast<const float4*>(xn + cr * T_LEN + toff);
                }
            }

            // 2) PLIF scan of chunk c-1 (64 cols; chunk 7 done in epilogue)
            if (c > 0 && sid < C_OUT) {
                const float* yrow = &ybuf[b ^ 1][sid * YSTRIDE];
                #pragma unroll 4
                for (int t = 0; t < TC; ++t) {
                    const float xt = fmaf(yrow[t], inv_c, bb_c);   // BN
                    v = fmaf(xt - v, decay, v);                    // v += (x-v)*decay
                    const bool s = (v >= 1.0f);
                    cnt += s ? 1.0f : 0.0f;
                    v = s ? 0.0f : v;
                }
            }

            // 3) write staged chunk -> xs[b^1] (FIR reads xs[b]; disjoint)
            if (c < NCHUNK - 1) {
                #pragma unroll
                for (int s = 0; s < 10; ++s) {
                    const int i  = s * 128 + sid;
                    const int cr = i >> 4, t4 = i & 15;
                    *reinterpret_cast<float4*>(&xs[b ^ 1][(cr + 32) * TC + t4 * 4]) = pf[s];
                }
            }
        }
        __syncthreads();   // single barrier per chunk
    }

    // epilogue: scan chunk 7 (52 cols) from ybuf[1]
    if (tid >= NFIR) {
        const int sid = tid - NFIR;
        if (sid < C_OUT) {
            const float* yrow = &ybuf[1][sid * YSTRIDE];
            #pragma unroll 4
            for (int t = 0; t < 52; ++t) {
                const float xt = fmaf(yrow[t], inv_c, bb_c);
                v = fmaf(xt - v, decay, v);
                const bool s = (v >= 1.0f);
                cnt += s ? 1.0f : 0.0f;
                v = s ? 0.0f : v;
            }
            feat[sid] = cnt * (1.0f / 500.0f);
        }
    }
    __syncthreads();

    if (tid < 3) {
        float o = fc_b[tid];
        #pragma unroll 3
        for (int cc = 0; cc < C_OUT; ++cc)
            o = fmaf(feat[cc], fc_w[tid * C_OUT + cc], o);
        out[n * 3 + tid] = o;
    }
}

extern "C" void kernel_launch(void* const* d_in, const int* in_sizes, int n_in,
                              void* d_out, int out_size, void* d_ws, size_t ws_size,
                              hipStream_t stream)
{
    const float* x        = (const float*)d_in[0];
    const float* conv_w   = (const float*)d_in[1];
    const float* conv_b   = (const float*)d_in[2];
    const float* bn_gamma = (const float*)d_in[3];
    const float* bn_beta  = (const float*)d_in[4];
    const float* bn_mean  = (const float*)d_in[5];
    const float* bn_var   = (const float*)d_in[6];
    const float* plif_w   = (const float*)d_in[7];
    const float* fc_w     = (const float*)d_in[8];
    const float* fc_b     = (const float*)d_in[9];
    float* out            = (float*)d_out;

    snn_fused_ps_kernel<<<1024, NTH, 0, stream>>>(
        x, conv_w, conv_b, bn_gamma, bn_beta, bn_mean, bn_var,
        plif_w, fc_w, fc_b, out);
}